// Round 6
// baseline (256.271 us; speedup 1.0000x reference)
//
#include <hip/hip_runtime.h>
#include <hip/hip_bf16.h>
#include <stdint.h>

#define BB 16
#define NN 32
#define TT 256
#define HH 256
#define DD 512
#define EPSF 1e-5f

#define TROWS 32      // fused T-tile rows per block (proven best geometry)
#define ROWB  512     // bytes per A row (256 bf16, no pad; XOR-swizzled)

typedef __attribute__((ext_vector_type(8))) short short8;
typedef __attribute__((ext_vector_type(4))) float floatx4;

__device__ __forceinline__ unsigned short f2bf(float f) {
    union { float f; unsigned u; } v; v.f = f;
    unsigned u = v.u;
    unsigned r = u + 0x7FFFu + ((u >> 16) & 1u);   // RNE
    return (unsigned short)(r >> 16);
}
__device__ __forceinline__ float bf2f(unsigned short h) {
    union { unsigned u; float f; } v; v.u = ((unsigned)h) << 16;
    return v.f;
}

// Truncation-based split of two f32 -> packed bf16-hi pair + bf16-lo pair.
// hi = trunc16(f); lo = trunc16(f - hi). (R2: absmax identical to RNE split)
__device__ __forceinline__ void split2(float f0, float f1, unsigned& hp, unsigned& lp) {
    union { float f; unsigned u; } a0, a1, r0, r1;
    a0.f = f0; a1.f = f1;
    const unsigned h0 = a0.u & 0xFFFF0000u;
    const unsigned h1 = a1.u & 0xFFFF0000u;
    union { unsigned u; float f; } b0, b1;
    b0.u = h0; b1.u = h1;
    r0.f = f0 - b0.f;
    r1.f = f1 - b1.f;
    hp = (a0.u >> 16) | h1;
    lp = (r0.u >> 16) | (r1.u & 0xFFFF0000u);
}

// ---------------------------------------------------------------------------
// Kernel 1: prep (unchanged).
//  blocks 0..1151   : h = relu(x@W+b). 8 rows x 128 cols per block.
//  blocks 1152..1167: pack W3 -> W3p_hi / W3p_lo (bf16 split, B-frag order)
// ---------------------------------------------------------------------------
__global__ __launch_bounds__(256) void prep_kernel(
    const float* __restrict__ x1, const float* __restrict__ x2,
    const float* __restrict__ W1, const float* __restrict__ b1,
    const float* __restrict__ W2, const float* __restrict__ b2,
    const float* __restrict__ W3,
    float* __restrict__ h1, float* __restrict__ h2,
    unsigned short* __restrict__ W3p_hi, unsigned short* __restrict__ W3p_lo)
{
    const int blk = blockIdx.x;
    const int tid = threadIdx.x;

    if (blk >= 1152) {
        // W3p flat idx o = ((CT*8 + kk)*64 + lane)*8 + j
        //   element = W3[kk*32 + (lane>>4)*8 + j][CT*16 + (lane&15)]
        const int p  = (blk - 1152) * 256 + tid;   // 0..4095
        const int o0 = p * 16;
        unsigned short thi[16], tlo[16];
#pragma unroll
        for (int e = 0; e < 16; ++e) {
            const int o    = o0 + e;
            const int j    = o & 7;
            const int lane = (o >> 3) & 63;
            const int kk   = (o >> 9) & 7;
            const int ct   = o >> 12;
            const int krow = kk * 32 + (lane >> 4) * 8 + j;
            const int col  = ct * 16 + (lane & 15);
            const float w  = W3[krow * HH + col];
            const unsigned short hi = f2bf(w);
            thi[e] = hi;
            tlo[e] = f2bf(w - bf2f(hi));
        }
        unsigned wh[8], wl[8];
#pragma unroll
        for (int e = 0; e < 8; ++e) {
            wh[e] = (unsigned)thi[2 * e] | ((unsigned)thi[2 * e + 1] << 16);
            wl[e] = (unsigned)tlo[2 * e] | ((unsigned)tlo[2 * e + 1] << 16);
        }
        uint4* dh = reinterpret_cast<uint4*>(W3p_hi + o0);
        dh[0] = make_uint4(wh[0], wh[1], wh[2], wh[3]);
        dh[1] = make_uint4(wh[4], wh[5], wh[6], wh[7]);
        uint4* dl = reinterpret_cast<uint4*>(W3p_lo + o0);
        dl[0] = make_uint4(wl[0], wl[1], wl[2], wl[3]);
        dl[1] = make_uint4(wl[4], wl[5], wl[6], wl[7]);
        return;
    }

    __shared__ float xs[8][DD];   // 16 KB

    const int rowgrp  = blk >> 1;
    const int colbase = (blk & 1) * 128;

    const float* x; const float* W; const float* bias; float* h; int row0;
    if (rowgrp < 64) { x = x1; W = W1; bias = b1; h = h1; row0 = rowgrp * 8; }
    else             { x = x2; W = W2; bias = b2; h = h2; row0 = (rowgrp - 64) * 8; }

    {
        const float4* xg = reinterpret_cast<const float4*>(x + (size_t)row0 * DD);
        float4* xl = reinterpret_cast<float4*>(&xs[0][0]);
#pragma unroll
        for (int i = 0; i < 4; ++i) xl[tid + 256 * i] = xg[tid + 256 * i];
    }
    __syncthreads();

    const int jj  = tid & 127;
    const int rh  = tid >> 7;          // wave-uniform
    const int col = colbase + jj;

    float acc[4] = {0.0f, 0.0f, 0.0f, 0.0f};
    const float* Wp = W + col;

    for (int k = 0; k < DD; k += 8) {
        float w[8];
#pragma unroll
        for (int q = 0; q < 8; ++q) w[q] = Wp[(size_t)(k + q) * HH];
#pragma unroll
        for (int r = 0; r < 4; ++r) {
            const float4 xa = *reinterpret_cast<const float4*>(&xs[rh * 4 + r][k]);
            const float4 xb = *reinterpret_cast<const float4*>(&xs[rh * 4 + r][k + 4]);
            float s = acc[r];
            s = fmaf(xa.x, w[0], s); s = fmaf(xa.y, w[1], s);
            s = fmaf(xa.z, w[2], s); s = fmaf(xa.w, w[3], s);
            s = fmaf(xb.x, w[4], s); s = fmaf(xb.y, w[5], s);
            s = fmaf(xb.z, w[6], s); s = fmaf(xb.w, w[7], s);
            acc[r] = s;
        }
    }

    const float bb = bias[col];
#pragma unroll
    for (int r = 0; r < 4; ++r) {
        const float v = acc[r] + bb;
        h[(size_t)(row0 + rh * 4 + r) * HH + col] = v > 0.0f ? v : 0.0f;
    }
}

// ---------------------------------------------------------------------------
// Kernel 2: fused MFMA main — TROWS=32 tiles, 512 threads = 8 waves.
// Same per-block totals as R5 (best), spread over 2x the waves:
//   wave w -> rows 0..31 (2 rt) x cols [w*32, w*32+32) (2 ct).
//   4 blocks/CU (thread-limited) x 8 waves = 32 waves/CU target occupancy.
// LDS = 32,768 B (A hi/lo, XOR-swizzled, no pad); LN1 buffers overlaid.
// ---------------------------------------------------------------------------
__global__ __launch_bounds__(512) void fused_mfma_kernel(
    const float* __restrict__ h1, const float* __restrict__ h2,
    const unsigned short* __restrict__ W3p_hi,
    const unsigned short* __restrict__ W3p_lo,
    const float* __restrict__ b3,
    const float* __restrict__ g0, const float* __restrict__ be0,
    const float* __restrict__ g1, const float* __restrict__ be1,
    float* __restrict__ out)
{
    __shared__ __align__(16) unsigned short Ah_s[TROWS * 256];  // 16,384 B
    __shared__ __align__(16) unsigned short Al_s[TROWS * 256];  // 16,384 B

    const int tid  = threadIdx.x;
    const int wave = tid >> 6;          // 0..7
    const int lane = tid & 63;
    const int blk  = blockIdx.x;
    const int tile = blk & 7;           // 8 tiles of 32 rows
    const int n    = (blk >> 3) & 31;
    const int b    = blk >> 8;

    // ---- Phase A: Hadamard + LN0 -> swizzled trunc-split bf16 A-tiles -----
    // 4 rows per wave (rows wave*4 .. wave*4+3).
    {
        const float* h1row = h1 + ((size_t)b * NN + n) * HH;
        const float4 h1v  = *reinterpret_cast<const float4*>(h1row + 4 * lane);
        const float4 g0v  = *reinterpret_cast<const float4*>(g0  + 4 * lane);
        const float4 be0v = *reinterpret_cast<const float4*>(be0 + 4 * lane);
        const float* h2b  = h2 + ((size_t)b * TT + tile * TROWS) * HH;

        float4 v[4]; float s[4], q[4];
#pragma unroll
        for (int i = 0; i < 4; ++i) {
            const int r = wave * 4 + i;
            v[i] = *reinterpret_cast<const float4*>(h2b + (size_t)r * HH + 4 * lane);
            v[i].x *= h1v.x; v[i].y *= h1v.y; v[i].z *= h1v.z; v[i].w *= h1v.w;
            s[i] = v[i].x + v[i].y + v[i].z + v[i].w;
            q[i] = v[i].x * v[i].x + v[i].y * v[i].y
                 + v[i].z * v[i].z + v[i].w * v[i].w;
        }
        // 8 interleaved shuffle chains -> latency hidden by ILP
#pragma unroll
        for (int off = 32; off >= 1; off >>= 1) {
#pragma unroll
            for (int i = 0; i < 4; ++i) {
                s[i] += __shfl_xor(s[i], off, 64);
                q[i] += __shfl_xor(q[i], off, 64);
            }
        }
#pragma unroll
        for (int i = 0; i < 4; ++i) {
            const int r = wave * 4 + i;
            const float mu  = s[i] * (1.0f / HH);
            const float var = q[i] * (1.0f / HH) - mu * mu;
            const float rs  = rsqrtf(var + EPSF);
            float af0 = (v[i].x - mu) * rs * g0v.x + be0v.x;
            float af1 = (v[i].y - mu) * rs * g0v.y + be0v.y;
            float af2 = (v[i].z - mu) * rs * g0v.z + be0v.z;
            float af3 = (v[i].w - mu) * rs * g0v.w + be0v.w;
            unsigned hp0, lp0, hp1, lp1;
            split2(af0, af1, hp0, lp0);
            split2(af2, af3, hp1, lp1);
            const int byteoff = (lane * 8) ^ ((r & 7) << 4);   // XOR swizzle
            *reinterpret_cast<uint2*>(
                reinterpret_cast<char*>(Ah_s) + r * ROWB + byteoff)
                = make_uint2(hp0, hp1);
            *reinterpret_cast<uint2*>(
                reinterpret_cast<char*>(Al_s) + r * ROWB + byteoff)
                = make_uint2(lp0, lp1);
        }
    }
    __syncthreads();

    // ---- MFMA GEMM: wave -> rows 0..31 (2 rt), cols [wave*32, +32) (2 ct) -
    const int m  = lane & 15;
    const int qd = lane >> 4;

    floatx4 acc[2][2];
#pragma unroll
    for (int ct = 0; ct < 2; ++ct) {
        const float bv = b3[wave * 32 + ct * 16 + m];
#pragma unroll
        for (int rt = 0; rt < 2; ++rt) {
            acc[rt][ct][0] = bv; acc[rt][ct][1] = bv;
            acc[rt][ct][2] = bv; acc[rt][ct][3] = bv;
        }
    }

    const char* AhB = reinterpret_cast<const char*>(Ah_s);
    const char* AlB = reinterpret_cast<const char*>(Al_s);

#pragma unroll 2
    for (int kk = 0; kk < 8; ++kk) {
        short8 bh[2], bl[2];
#pragma unroll
        for (int ct = 0; ct < 2; ++ct) {
            const size_t off = ((size_t)((wave * 2 + ct) * 8 + kk) * 64 + lane) * 8;
            bh[ct] = *reinterpret_cast<const short8*>(W3p_hi + off);
            bl[ct] = *reinterpret_cast<const short8*>(W3p_lo + off);
        }
        const int swzoff = (kk * 64 + qd * 16) ^ ((m & 7) << 4);   // XOR swizzle
#pragma unroll
        for (int rt = 0; rt < 2; ++rt) {
            const int rowbyte = (rt * 16 + m) * ROWB;
            const short8 ah = *reinterpret_cast<const short8*>(AhB + rowbyte + swzoff);
            const short8 al = *reinterpret_cast<const short8*>(AlB + rowbyte + swzoff);
#pragma unroll
            for (int ct = 0; ct < 2; ++ct) {
                floatx4 c = acc[rt][ct];
                c = __builtin_amdgcn_mfma_f32_16x16x32_bf16(ah, bh[ct], c, 0, 0, 0);
                c = __builtin_amdgcn_mfma_f32_16x16x32_bf16(al, bh[ct], c, 0, 0, 0);
                c = __builtin_amdgcn_mfma_f32_16x16x32_bf16(ah, bl[ct], c, 0, 0, 0);
                acc[rt][ct] = c;
            }
        }
    }

    // ---- LN1 partials from registers ---------------------------------------
    // acc element (rt,ct,reg) = Y[row = rt*16 + qd*4 + reg][col = wave*32 + ct*16 + m]
    float ssum[8], qsum[8];       // [rt*4 + reg]
    {
#pragma unroll
        for (int rt = 0; rt < 2; ++rt)
#pragma unroll
            for (int reg = 0; reg < 4; ++reg) {
                float s = 0.0f, q = 0.0f;
#pragma unroll
                for (int ct = 0; ct < 2; ++ct) {
                    const float y = acc[rt][ct][reg];
                    s += y; q = fmaf(y, y, q);
                }
                ssum[rt * 4 + reg] = s; qsum[rt * 4 + reg] = q;
            }
#pragma unroll
        for (int off = 1; off < 16; off <<= 1) {
#pragma unroll
            for (int e = 0; e < 8; ++e) {
                ssum[e] += __shfl_xor(ssum[e], off, 64);
                qsum[e] += __shfl_xor(qsum[e], off, 64);
            }
        }
    }

    // A region is dead now; overlay LN1 exchange buffers on it.
    __syncthreads();                                   // all A reads retired
    float2* Spart = reinterpret_cast<float2*>(Ah_s);   // [TROWS][8]
    float2* LNP   = reinterpret_cast<float2*>(Al_s);   // [TROWS]

    if (m == 0) {
#pragma unroll
        for (int rt = 0; rt < 2; ++rt)
#pragma unroll
            for (int reg = 0; reg < 4; ++reg) {
                const int row = rt * 16 + qd * 4 + reg;
                Spart[row * 8 + wave] = make_float2(ssum[rt * 4 + reg], qsum[rt * 4 + reg]);
            }
    }
    __syncthreads();

    if (tid < TROWS) {
        float s = 0.0f, q = 0.0f;
#pragma unroll
        for (int w = 0; w < 8; ++w) {
            const float2 p = Spart[tid * 8 + w];
            s += p.x; q += p.y;
        }
        const float mu  = s * (1.0f / HH);
        const float var = q * (1.0f / HH) - mu * mu;
        LNP[tid] = make_float2(mu, rsqrtf(var + EPSF));
    }
    __syncthreads();

    // ---- apply LN1 + relu + store straight from acc -----------------------
    {
        const int colb = wave * 32;
        float g1c[2], be1c[2];
#pragma unroll
        for (int ct = 0; ct < 2; ++ct) {
            g1c[ct]  = g1[colb + ct * 16 + m];
            be1c[ct] = be1[colb + ct * 16 + m];
        }
        float* outb = out + (((size_t)b * NN + n) * TT + tile * TROWS) * HH;

#pragma unroll
        for (int rt = 0; rt < 2; ++rt)
#pragma unroll
            for (int reg = 0; reg < 4; ++reg) {
                const int row = rt * 16 + qd * 4 + reg;
                const float2 p = LNP[row];   // (mu, rs)
#pragma unroll
                for (int ct = 0; ct < 2; ++ct) {
                    const float y = acc[rt][ct][reg];
                    const float o = fmaxf((y - p.x) * p.y * g1c[ct] + be1c[ct], 0.0f);
                    outb[(size_t)row * HH + colb + ct * 16 + m] = o;
                }
            }
    }
}

// ---------------------------------------------------------------------------
extern "C" void kernel_launch(void* const* d_in, const int* in_sizes, int n_in,
                              void* d_out, int out_size, void* d_ws, size_t ws_size,
                              hipStream_t stream) {
    const float* x1  = (const float*)d_in[0];
    const float* x2  = (const float*)d_in[1];
    const float* W1  = (const float*)d_in[2];
    const float* b1  = (const float*)d_in[3];
    const float* W2  = (const float*)d_in[4];
    const float* b2  = (const float*)d_in[5];
    const float* W3  = (const float*)d_in[6];
    const float* b3  = (const float*)d_in[7];
    const float* g0  = (const float*)d_in[8];
    const float* be0 = (const float*)d_in[9];
    const float* g1  = (const float*)d_in[10];
    const float* be1 = (const float*)d_in[11];
    float* out = (float*)d_out;

    // Workspace: h1 (0.5 MB) | h2 (4 MB) | W3p_hi (128 KB) | W3p_lo (128 KB)
    float* h1 = (float*)d_ws;
    float* h2 = h1 + (size_t)BB * NN * HH;
    unsigned short* W3p_hi = (unsigned short*)(h2 + (size_t)BB * TT * HH);
    unsigned short* W3p_lo = W3p_hi + (size_t)HH * HH;

    hipLaunchKernelGGL(prep_kernel, dim3(1168), dim3(256), 0, stream,
                       x1, x2, W1, b1, W2, b2, W3, h1, h2, W3p_hi, W3p_lo);

    hipLaunchKernelGGL(fused_mfma_kernel, dim3(4096), dim3(512), 0, stream,
                       h1, h2, W3p_hi, W3p_lo, b3, g0, be0, g1, be1, out);
}

// Round 8
// 244.997 us; speedup vs baseline: 1.0460x; 1.0460x over previous
//
#include <hip/hip_runtime.h>
#include <hip/hip_bf16.h>
#include <stdint.h>

#define BB 16
#define NN 32
#define TT 256
#define HH 256
#define DD 512
#define EPSF 1e-5f

#define TROWS 32      // fused T-tile rows per block (proven best geometry)
#define ROWB  512     // bytes per A row (256 bf16, no pad; XOR-swizzled)

typedef __attribute__((ext_vector_type(8))) short short8;
typedef __attribute__((ext_vector_type(4))) float floatx4;

__device__ __forceinline__ unsigned short f2bf(float f) {
    union { float f; unsigned u; } v; v.f = f;
    unsigned u = v.u;
    unsigned r = u + 0x7FFFu + ((u >> 16) & 1u);   // RNE
    return (unsigned short)(r >> 16);
}
__device__ __forceinline__ float bf2f(unsigned short h) {
    union { unsigned u; float f; } v; v.u = ((unsigned)h) << 16;
    return v.f;
}

// Truncation-based split of two f32 -> packed bf16-hi pair + bf16-lo pair.
// hi = trunc16(f); lo = trunc16(f - hi). (R2: absmax identical to RNE split)
__device__ __forceinline__ void split2(float f0, float f1, unsigned& hp, unsigned& lp) {
    union { float f; unsigned u; } a0, a1, r0, r1;
    a0.f = f0; a1.f = f1;
    const unsigned h0 = a0.u & 0xFFFF0000u;
    const unsigned h1 = a1.u & 0xFFFF0000u;
    union { unsigned u; float f; } b0, b1;
    b0.u = h0; b1.u = h1;
    r0.f = f0 - b0.f;
    r1.f = f1 - b1.f;
    hp = (a0.u >> 16) | h1;
    lp = (r0.u >> 16) | (r1.u & 0xFFFF0000u);
}

// ---- DPP reductions: VALU-pipe cross-lane adds (no DS/shuffle traffic) ----
// ctrl must be a compile-time constant -> template parameter.
// row_shr:N = 0x110+N, row_bcast15 = 0x142, row_bcast31 = 0x143.
// bound_ctrl=true -> invalid source lanes read 0 (additive identity).
template <int CTRL>
__device__ __forceinline__ float dpp_add(float x) {
    const int t = __builtin_amdgcn_update_dpp(
        0, __float_as_int(x), CTRL, 0xF, 0xF, true);
    return x + __int_as_float(t);
}

// One reduction stage applied to 8 interleaved chains (ILP).
template <int CTRL>
__device__ __forceinline__ void dpp_stage8(float* s, float* q, int nn) {
#pragma unroll
    for (int i = 0; i < 4; ++i) {
        if (i < nn) { s[i] = dpp_add<CTRL>(s[i]); q[i] = dpp_add<CTRL>(q[i]); }
    }
}

// ---------------------------------------------------------------------------
// Kernel 1: prep (unchanged).
//  blocks 0..1151   : h = relu(x@W+b). 8 rows x 128 cols per block.
//  blocks 1152..1167: pack W3 -> W3p_hi / W3p_lo (bf16 split, B-frag order)
// ---------------------------------------------------------------------------
__global__ __launch_bounds__(256) void prep_kernel(
    const float* __restrict__ x1, const float* __restrict__ x2,
    const float* __restrict__ W1, const float* __restrict__ b1,
    const float* __restrict__ W2, const float* __restrict__ b2,
    const float* __restrict__ W3,
    float* __restrict__ h1, float* __restrict__ h2,
    unsigned short* __restrict__ W3p_hi, unsigned short* __restrict__ W3p_lo)
{
    const int blk = blockIdx.x;
    const int tid = threadIdx.x;

    if (blk >= 1152) {
        // W3p flat idx o = ((CT*8 + kk)*64 + lane)*8 + j
        //   element = W3[kk*32 + (lane>>4)*8 + j][CT*16 + (lane&15)]
        const int p  = (blk - 1152) * 256 + tid;   // 0..4095
        const int o0 = p * 16;
        unsigned short thi[16], tlo[16];
#pragma unroll
        for (int e = 0; e < 16; ++e) {
            const int o    = o0 + e;
            const int j    = o & 7;
            const int lane = (o >> 3) & 63;
            const int kk   = (o >> 9) & 7;
            const int ct   = o >> 12;
            const int krow = kk * 32 + (lane >> 4) * 8 + j;
            const int col  = ct * 16 + (lane & 15);
            const float w  = W3[krow * HH + col];
            const unsigned short hi = f2bf(w);
            thi[e] = hi;
            tlo[e] = f2bf(w - bf2f(hi));
        }
        unsigned wh[8], wl[8];
#pragma unroll
        for (int e = 0; e < 8; ++e) {
            wh[e] = (unsigned)thi[2 * e] | ((unsigned)thi[2 * e + 1] << 16);
            wl[e] = (unsigned)tlo[2 * e] | ((unsigned)tlo[2 * e + 1] << 16);
        }
        uint4* dh = reinterpret_cast<uint4*>(W3p_hi + o0);
        dh[0] = make_uint4(wh[0], wh[1], wh[2], wh[3]);
        dh[1] = make_uint4(wh[4], wh[5], wh[6], wh[7]);
        uint4* dl = reinterpret_cast<uint4*>(W3p_lo + o0);
        dl[0] = make_uint4(wl[0], wl[1], wl[2], wl[3]);
        dl[1] = make_uint4(wl[4], wl[5], wl[6], wl[7]);
        return;
    }

    __shared__ float xs[8][DD];   // 16 KB

    const int rowgrp  = blk >> 1;
    const int colbase = (blk & 1) * 128;

    const float* x; const float* W; const float* bias; float* h; int row0;
    if (rowgrp < 64) { x = x1; W = W1; bias = b1; h = h1; row0 = rowgrp * 8; }
    else             { x = x2; W = W2; bias = b2; h = h2; row0 = (rowgrp - 64) * 8; }

    {
        const float4* xg = reinterpret_cast<const float4*>(x + (size_t)row0 * DD);
        float4* xl = reinterpret_cast<float4*>(&xs[0][0]);
#pragma unroll
        for (int i = 0; i < 4; ++i) xl[tid + 256 * i] = xg[tid + 256 * i];
    }
    __syncthreads();

    const int jj  = tid & 127;
    const int rh  = tid >> 7;          // wave-uniform
    const int col = colbase + jj;

    float acc[4] = {0.0f, 0.0f, 0.0f, 0.0f};
    const float* Wp = W + col;

    for (int k = 0; k < DD; k += 8) {
        float w[8];
#pragma unroll
        for (int q = 0; q < 8; ++q) w[q] = Wp[(size_t)(k + q) * HH];
#pragma unroll
        for (int r = 0; r < 4; ++r) {
            const float4 xa = *reinterpret_cast<const float4*>(&xs[rh * 4 + r][k]);
            const float4 xb = *reinterpret_cast<const float4*>(&xs[rh * 4 + r][k + 4]);
            float s = acc[r];
            s = fmaf(xa.x, w[0], s); s = fmaf(xa.y, w[1], s);
            s = fmaf(xa.z, w[2], s); s = fmaf(xa.w, w[3], s);
            s = fmaf(xb.x, w[4], s); s = fmaf(xb.y, w[5], s);
            s = fmaf(xb.z, w[6], s); s = fmaf(xb.w, w[7], s);
            acc[r] = s;
        }
    }

    const float bb = bias[col];
#pragma unroll
    for (int r = 0; r < 4; ++r) {
        const float v = acc[r] + bb;
        h[(size_t)(row0 + rh * 4 + r) * HH + col] = v > 0.0f ? v : 0.0f;
    }
}

// ---------------------------------------------------------------------------
// Kernel 2: fused MFMA main — R5 geometry (best: 90.2 µs), with ALL cross-lane
// reductions moved from DS-pipe shuffles (__shfl_xor -> ds_bpermute, ~160 DS
// ops + 6-deep ~30cy-latency chains per wave) to DPP VALU adds (~4cy hops,
// zero DS traffic).
//   LN0: full-64-lane DPP sum (row_shr 1/2/4/8 + bcast15 + bcast31) +
//        readlane(63) broadcast.
//   LN1: 16-lane row_shr chain; lane m==15 holds the group sum -> writes Spart.
// Everything else identical to R5.
// ---------------------------------------------------------------------------
__global__ __launch_bounds__(256) void fused_mfma_kernel(
    const float* __restrict__ h1, const float* __restrict__ h2,
    const unsigned short* __restrict__ W3p_hi,
    const unsigned short* __restrict__ W3p_lo,
    const float* __restrict__ b3,
    const float* __restrict__ g0, const float* __restrict__ be0,
    const float* __restrict__ g1, const float* __restrict__ be1,
    float* __restrict__ out)
{
    __shared__ __align__(16) unsigned short Ah_s[TROWS * 256];  // 16,384 B
    __shared__ __align__(16) unsigned short Al_s[TROWS * 256];  // 16,384 B

    const int tid  = threadIdx.x;
    const int wave = tid >> 6;
    const int lane = tid & 63;
    const int blk  = blockIdx.x;
    const int tile = blk & 7;           // 8 tiles of 32 rows
    const int n    = (blk >> 3) & 31;
    const int b    = blk >> 8;

    // ---- Phase A: Hadamard + LN0 -> swizzled trunc-split bf16 A-tiles -----
    {
        const float* h1row = h1 + ((size_t)b * NN + n) * HH;
        const float4 h1v  = *reinterpret_cast<const float4*>(h1row + 4 * lane);
        const float4 g0v  = *reinterpret_cast<const float4*>(g0  + 4 * lane);
        const float4 be0v = *reinterpret_cast<const float4*>(be0 + 4 * lane);
        const float* h2b  = h2 + ((size_t)b * TT + tile * TROWS) * HH;

#pragma unroll
        for (int half = 0; half < 2; ++half) {
            float4 v[4]; float s[4], q[4];
#pragma unroll
            for (int i = 0; i < 4; ++i) {
                const int r = wave * 8 + half * 4 + i;
                v[i] = *reinterpret_cast<const float4*>(h2b + (size_t)r * HH + 4 * lane);
                v[i].x *= h1v.x; v[i].y *= h1v.y; v[i].z *= h1v.z; v[i].w *= h1v.w;
                s[i] = v[i].x + v[i].y + v[i].z + v[i].w;
                q[i] = v[i].x * v[i].x + v[i].y * v[i].y
                     + v[i].z * v[i].z + v[i].w * v[i].w;
            }
            // 64-lane DPP sum: 8 interleaved VALU chains (no DS traffic)
            dpp_stage8<0x111>(s, q, 4);
            dpp_stage8<0x112>(s, q, 4);
            dpp_stage8<0x114>(s, q, 4);
            dpp_stage8<0x118>(s, q, 4);
            dpp_stage8<0x142>(s, q, 4);
            dpp_stage8<0x143>(s, q, 4);
#pragma unroll
            for (int i = 0; i < 4; ++i) {
                const int r = wave * 8 + half * 4 + i;
                const float st = __int_as_float(
                    __builtin_amdgcn_readlane(__float_as_int(s[i]), 63));
                const float qt = __int_as_float(
                    __builtin_amdgcn_readlane(__float_as_int(q[i]), 63));
                const float mu  = st * (1.0f / HH);
                const float var = qt * (1.0f / HH) - mu * mu;
                const float rs  = rsqrtf(var + EPSF);
                float af0 = (v[i].x - mu) * rs * g0v.x + be0v.x;
                float af1 = (v[i].y - mu) * rs * g0v.y + be0v.y;
                float af2 = (v[i].z - mu) * rs * g0v.z + be0v.z;
                float af3 = (v[i].w - mu) * rs * g0v.w + be0v.w;
                unsigned hp0, lp0, hp1, lp1;
                split2(af0, af1, hp0, lp0);
                split2(af2, af3, hp1, lp1);
                const int byteoff = (lane * 8) ^ ((r & 7) << 4);   // XOR swizzle
                *reinterpret_cast<uint2*>(
                    reinterpret_cast<char*>(Ah_s) + r * ROWB + byteoff)
                    = make_uint2(hp0, hp1);
                *reinterpret_cast<uint2*>(
                    reinterpret_cast<char*>(Al_s) + r * ROWB + byteoff)
                    = make_uint2(lp0, lp1);
            }
        }
    }
    __syncthreads();

    // ---- MFMA GEMM: wave -> rows 0..31 (2 rt), cols [wave*64, +64) (4 ct) -
    const int m  = lane & 15;
    const int qd = lane >> 4;

    floatx4 acc[2][4];
#pragma unroll
    for (int ct = 0; ct < 4; ++ct) {
        const float bv = b3[wave * 64 + ct * 16 + m];
#pragma unroll
        for (int rt = 0; rt < 2; ++rt) {
            acc[rt][ct][0] = bv; acc[rt][ct][1] = bv;
            acc[rt][ct][2] = bv; acc[rt][ct][3] = bv;
        }
    }

    const char* AhB = reinterpret_cast<const char*>(Ah_s);
    const char* AlB = reinterpret_cast<const char*>(Al_s);

#pragma unroll 2
    for (int kk = 0; kk < 8; ++kk) {
        short8 bh[4], bl[4];
#pragma unroll
        for (int ct = 0; ct < 4; ++ct) {
            const size_t off = ((size_t)((wave * 4 + ct) * 8 + kk) * 64 + lane) * 8;
            bh[ct] = *reinterpret_cast<const short8*>(W3p_hi + off);
            bl[ct] = *reinterpret_cast<const short8*>(W3p_lo + off);
        }
        const int swzoff = (kk * 64 + qd * 16) ^ ((m & 7) << 4);   // XOR swizzle
#pragma unroll
        for (int rt = 0; rt < 2; ++rt) {
            const int rowbyte = (rt * 16 + m) * ROWB;
            const short8 ah = *reinterpret_cast<const short8*>(AhB + rowbyte + swzoff);
            const short8 al = *reinterpret_cast<const short8*>(AlB + rowbyte + swzoff);
#pragma unroll
            for (int ct = 0; ct < 4; ++ct) {
                floatx4 c = acc[rt][ct];
                c = __builtin_amdgcn_mfma_f32_16x16x32_bf16(ah, bh[ct], c, 0, 0, 0);
                c = __builtin_amdgcn_mfma_f32_16x16x32_bf16(al, bh[ct], c, 0, 0, 0);
                c = __builtin_amdgcn_mfma_f32_16x16x32_bf16(ah, bl[ct], c, 0, 0, 0);
                acc[rt][ct] = c;
            }
        }
    }

    // ---- LN1 partials from registers (DPP 16-lane reduce over m) ----------
    // acc element (rt,ct,reg) = Y[row = rt*16 + qd*4 + reg][col = wave*64 + ct*16 + m]
    float ssum[8], qsum[8];       // [rt*4 + reg]
    {
#pragma unroll
        for (int rt = 0; rt < 2; ++rt)
#pragma unroll
            for (int reg = 0; reg < 4; ++reg) {
                float s = 0.0f, q = 0.0f;
#pragma unroll
                for (int ct = 0; ct < 4; ++ct) {
                    const float y = acc[rt][ct][reg];
                    s += y; q = fmaf(y, y, q);
                }
                ssum[rt * 4 + reg] = s; qsum[rt * 4 + reg] = q;
            }
        dpp_stage8<0x111>(ssum, qsum, 4); dpp_stage8<0x111>(ssum + 4, qsum + 4, 4);
        dpp_stage8<0x112>(ssum, qsum, 4); dpp_stage8<0x112>(ssum + 4, qsum + 4, 4);
        dpp_stage8<0x114>(ssum, qsum, 4); dpp_stage8<0x114>(ssum + 4, qsum + 4, 4);
        dpp_stage8<0x118>(ssum, qsum, 4); dpp_stage8<0x118>(ssum + 4, qsum + 4, 4);
        // lane m==15 of each 16-group now holds the sum over m.
    }

    // A region is dead now; overlay LN1 exchange buffers on it.
    __syncthreads();                                   // all A reads retired
    float2* Spart = reinterpret_cast<float2*>(Ah_s);   // [TROWS][4]
    float2* LNP   = reinterpret_cast<float2*>(Al_s);   // [TROWS]

    if (m == 15) {
#pragma unroll
        for (int rt = 0; rt < 2; ++rt)
#pragma unroll
            for (int reg = 0; reg < 4; ++reg) {
                const int row = rt * 16 + qd * 4 + reg;
                Spart[row * 4 + wave] = make_float2(ssum[rt * 4 + reg], qsum[rt * 4 + reg]);
            }
    }
    __syncthreads();

    if (tid < TROWS) {
        float s = 0.0f, q = 0.0f;
#pragma unroll
        for (int w = 0; w < 4; ++w) {
            const float2 p = Spart[tid * 4 + w];
            s += p.x; q += p.y;
        }
        const float mu  = s * (1.0f / HH);
        const float var = q * (1.0f / HH) - mu * mu;
        LNP[tid] = make_float2(mu, rsqrtf(var + EPSF));
    }
    __syncthreads();

    // ---- apply LN1 + relu + store straight from acc -----------------------
    {
        const int colb = wave * 64;
        float g1c[4], be1c[4];
#pragma unroll
        for (int ct = 0; ct < 4; ++ct) {
            g1c[ct]  = g1[colb + ct * 16 + m];
            be1c[ct] = be1[colb + ct * 16 + m];
        }
        float* outb = out + (((size_t)b * NN + n) * TT + tile * TROWS) * HH;

#pragma unroll
        for (int rt = 0; rt < 2; ++rt)
#pragma unroll
            for (int reg = 0; reg < 4; ++reg) {
                const int row = rt * 16 + qd * 4 + reg;
                const float2 p = LNP[row];   // (mu, rs)
#pragma unroll
                for (int ct = 0; ct < 4; ++ct) {
                    const float y = acc[rt][ct][reg];
                    const float o = fmaxf((y - p.x) * p.y * g1c[ct] + be1c[ct], 0.0f);
                    outb[(size_t)row * HH + colb + ct * 16 + m] = o;
                }
            }
    }
}

// ---------------------------------------------------------------------------
extern "C" void kernel_launch(void* const* d_in, const int* in_sizes, int n_in,
                              void* d_out, int out_size, void* d_ws, size_t ws_size,
                              hipStream_t stream) {
    const float* x1  = (const float*)d_in[0];
    const float* x2  = (const float*)d_in[1];
    const float* W1  = (const float*)d_in[2];
    const float* b1  = (const float*)d_in[3];
    const float* W2  = (const float*)d_in[4];
    const float* b2  = (const float*)d_in[5];
    const float* W3  = (const float*)d_in[6];
    const float* b3  = (const float*)d_in[7];
    const float* g0  = (const float*)d_in[8];
    const float* be0 = (const float*)d_in[9];
    const float* g1  = (const float*)d_in[10];
    const float* be1 = (const float*)d_in[11];
    float* out = (float*)d_out;

    // Workspace: h1 (0.5 MB) | h2 (4 MB) | W3p_hi (128 KB) | W3p_lo (128 KB)
    float* h1 = (float*)d_ws;
    float* h2 = h1 + (size_t)BB * NN * HH;
    unsigned short* W3p_hi = (unsigned short*)(h2 + (size_t)BB * TT * HH);
    unsigned short* W3p_lo = W3p_hi + (size_t)HH * HH;

    hipLaunchKernelGGL(prep_kernel, dim3(1168), dim3(256), 0, stream,
                       x1, x2, W1, b1, W2, b2, W3, h1, h2, W3p_hi, W3p_lo);

    hipLaunchKernelGGL(fused_mfma_kernel, dim3(4096), dim3(256), 0, stream,
                       h1, h2, W3p_hi, W3p_lo, b3, g0, be0, g1, be1, out);
}